// Round 1
// baseline (3760.681 us; speedup 1.0000x reference)
//
#include <hip/hip_runtime.h>

#define N_NODES 50000
#define N_EDGES 800000
#define CH 128

// ---------------- degree / dinv ----------------
__global__ __launch_bounds__(256) void k_init_deg(float* deg) {
    int i = blockIdx.x * 256 + threadIdx.x;
    if (i < N_NODES) deg[i] = 1.0f;   // self-loop
}

__global__ __launch_bounds__(256) void k_count_deg(const int* __restrict__ dst,
                                                   float* __restrict__ deg) {
    int e = blockIdx.x * 256 + threadIdx.x;
    if (e < N_EDGES) atomicAdd(&deg[dst[e]], 1.0f);
}

__global__ __launch_bounds__(256) void k_dinv(float* deg) {
    int i = blockIdx.x * 256 + threadIdx.x;
    if (i < N_NODES) deg[i] = rsqrtf(deg[i]);   // deg >= 1 always
}

// ---------------- GEMM: HS = (X @ W) * dinv[row]; AGG = HS (self-loop init) ----------------
// 256 threads, 64 rows/block in 2 passes of 32. W + 32 x-rows staged in LDS.
// Per-thread 4 rows x 4 cols, float4 LDS reads.
__global__ __launch_bounds__(256) void k_gemm_scale(
        const float* __restrict__ X, const float* __restrict__ W,
        const float* __restrict__ dinv,
        float* __restrict__ HS, float* __restrict__ AGG) {
    __shared__ float Wl[CH * CH];     // 64 KB
    __shared__ float xs[32][CH];      // 16 KB  -> 80 KB total, 2 blocks/CU

    const int tid = threadIdx.x;
    for (int i = tid; i < CH * CH; i += 256) Wl[i] = W[i];

    const int tc = tid & 31;    // col group: cols tc*4 .. tc*4+3
    const int tr = tid >> 5;    // row group: rows tr*4 .. tr*4+3 (within pass)
    const int row0 = blockIdx.x * 64;

    for (int pass = 0; pass < 2; ++pass) {
        const int rbase = row0 + pass * 32;
        __syncthreads();   // covers Wl load (pass 0) and xs reuse (pass 1)
        #pragma unroll
        for (int p = 0; p < 4; ++p) {
            int f = tid + p * 256;          // 0..1023 float4 slots
            int r = f >> 5, c = f & 31;
            int grow = rbase + r;
            float4 v = make_float4(0.f, 0.f, 0.f, 0.f);
            if (grow < N_NODES) v = *(const float4*)&X[grow * CH + c * 4];
            *(float4*)&xs[r][c * 4] = v;
        }
        __syncthreads();

        float4 acc0 = {0,0,0,0}, acc1 = {0,0,0,0}, acc2 = {0,0,0,0}, acc3 = {0,0,0,0};
        #pragma unroll
        for (int k4 = 0; k4 < 32; ++k4) {
            float4 x0 = *(const float4*)&xs[tr * 4 + 0][k4 * 4];
            float4 x1 = *(const float4*)&xs[tr * 4 + 1][k4 * 4];
            float4 x2 = *(const float4*)&xs[tr * 4 + 2][k4 * 4];
            float4 x3 = *(const float4*)&xs[tr * 4 + 3][k4 * 4];
            #pragma unroll
            for (int kk = 0; kk < 4; ++kk) {
                float4 w = *(const float4*)&Wl[(k4 * 4 + kk) * CH + tc * 4];
                float v0 = (&x0.x)[kk], v1 = (&x1.x)[kk], v2 = (&x2.x)[kk], v3 = (&x3.x)[kk];
                acc0.x += w.x * v0; acc0.y += w.y * v0; acc0.z += w.z * v0; acc0.w += w.w * v0;
                acc1.x += w.x * v1; acc1.y += w.y * v1; acc1.z += w.z * v1; acc1.w += w.w * v1;
                acc2.x += w.x * v2; acc2.y += w.y * v2; acc2.z += w.z * v2; acc2.w += w.w * v2;
                acc3.x += w.x * v3; acc3.y += w.y * v3; acc3.z += w.z * v3; acc3.w += w.w * v3;
            }
        }

        #pragma unroll
        for (int i = 0; i < 4; ++i) {
            int row = rbase + tr * 4 + i;
            if (row < N_NODES) {
                float di = dinv[row];
                float4 a = (i == 0) ? acc0 : (i == 1) ? acc1 : (i == 2) ? acc2 : acc3;
                float4 o = make_float4(a.x * di, a.y * di, a.z * di, a.w * di);
                *(float4*)&HS[row * CH + tc * 4]  = o;
                *(float4*)&AGG[row * CH + tc * 4] = o;
            }
        }
    }
}

// ---------------- edge scatter-add: AGG[dst] += HS[src]  (32 threads/edge, float4) ----------------
__global__ __launch_bounds__(256) void k_edge_agg(
        const int* __restrict__ ei, const float* __restrict__ HS,
        float* __restrict__ AGG) {
    unsigned gid = blockIdx.x * 256u + threadIdx.x;
    unsigned e = gid >> 5;
    if (e >= N_EDGES) return;
    int c4 = (gid & 31) * 4;
    int s = ei[e];
    int d = ei[N_EDGES + e];
    float4 v = *(const float4*)&HS[s * CH + c4];
    float* p = &AGG[d * CH + c4];
    atomicAdd(p + 0, v.x);
    atomicAdd(p + 1, v.y);
    atomicAdd(p + 2, v.z);
    atomicAdd(p + 3, v.w);
}

// ---------------- epilogue: OUT = relu(dinv[i] * AGG[i] + b) ----------------
__global__ __launch_bounds__(256) void k_epilogue(
        const float* __restrict__ AGG, const float* __restrict__ dinv,
        const float* __restrict__ b, float* __restrict__ OUT) {
    int i = blockIdx.x * 256 + threadIdx.x;     // one float4 per thread
    if (i >= N_NODES * (CH / 4)) return;
    int node = i >> 5;
    int c4 = (i & 31) * 4;
    float di = dinv[node];
    float4 v = *(const float4*)&AGG[node * CH + c4];
    float4 bb = *(const float4*)&b[c4];
    float4 o;
    o.x = fmaxf(v.x * di + bb.x, 0.f);
    o.y = fmaxf(v.y * di + bb.y, 0.f);
    o.z = fmaxf(v.z * di + bb.z, 0.f);
    o.w = fmaxf(v.w * di + bb.w, 0.f);
    *(float4*)&OUT[node * CH + c4] = o;
}

extern "C" void kernel_launch(void* const* d_in, const int* in_sizes, int n_in,
                              void* d_out, int out_size, void* d_ws, size_t ws_size,
                              hipStream_t stream) {
    const float* x  = (const float*)d_in[0];
    const int*   ei = (const int*)d_in[1];
    const float* W1 = (const float*)d_in[2];
    const float* b1 = (const float*)d_in[3];
    const float* W2 = (const float*)d_in[4];
    const float* b2 = (const float*)d_in[5];
    float* out = (float*)d_out;

    // workspace layout: dinv [50176 floats, aligned] | hs [N*CH floats]
    float* dinv = (float*)d_ws;
    float* hs   = dinv + 50176;

    const int gN   = (N_NODES + 255) / 256;            // 196
    const int gE   = (N_EDGES + 255) / 256;            // 3125
    const int gG   = (N_NODES + 63) / 64;              // 782
    const int gEA  = (N_EDGES * 32) / 256;             // 100000
    const int gEp  = (N_NODES * (CH / 4) + 255) / 256; // 6250

    // degree -> dinv
    k_init_deg<<<gN, 256, 0, stream>>>(dinv);
    k_count_deg<<<gE, 256, 0, stream>>>(ei + N_EDGES, dinv);
    k_dinv<<<gN, 256, 0, stream>>>(dinv);

    // ---- layer 1 ----
    k_gemm_scale<<<gG, 256, 0, stream>>>(x, W1, dinv, hs, out);   // out = AGG1 init (self-loop)
    k_edge_agg<<<gEA, 256, 0, stream>>>(ei, hs, out);
    k_epilogue<<<gEp, 256, 0, stream>>>(out, dinv, b1, hs);       // hs = relu(...) = layer2 input

    // ---- layer 2 ----
    k_gemm_scale<<<gG, 256, 0, stream>>>(hs, W2, dinv, hs, out);  // in-place HS2; out = AGG2 init
    k_edge_agg<<<gEA, 256, 0, stream>>>(ei, hs, out);
    k_epilogue<<<gEp, 256, 0, stream>>>(out, dinv, b2, out);      // final, in-place
}

// Round 2
// 1252.157 us; speedup vs baseline: 3.0034x; 3.0034x over previous
//
#include <hip/hip_runtime.h>

#define N_NODES 50000
#define N_EDGES 800000
#define CH 128
#define NB_SCAN 196   // ceil(N_NODES/256)

// ---------------- zero int degree array ----------------
__global__ __launch_bounds__(256) void k_zero(int* p, int n) {
    int i = blockIdx.x * 256 + threadIdx.x;
    if (i < n) p[i] = 0;
}

// ---------------- histogram of dst (in-degree, no self loop) ----------------
__global__ __launch_bounds__(256) void k_hist(const int* __restrict__ dst,
                                              int* __restrict__ deg) {
    int e = blockIdx.x * 256 + threadIdx.x;
    if (e < N_EDGES) atomicAdd(&deg[dst[e]], 1);
}

// ---------------- block-wise scan: rowptr[i] = block-exclusive, partials[b] = block sum ----------------
__global__ __launch_bounds__(256) void k_scan_block(const int* __restrict__ deg,
                                                    int* __restrict__ rowptr,
                                                    int* __restrict__ partials) {
    __shared__ int sm[256];
    int tid = threadIdx.x;
    int i = blockIdx.x * 256 + tid;
    int v = (i < N_NODES) ? deg[i] : 0;
    sm[tid] = v;
    __syncthreads();
    #pragma unroll
    for (int off = 1; off < 256; off <<= 1) {
        int t = (tid >= off) ? sm[tid - off] : 0;
        __syncthreads();
        sm[tid] += t;
        __syncthreads();
    }
    if (i < N_NODES) rowptr[i] = sm[tid] - v;     // exclusive within block
    if (tid == 255) partials[blockIdx.x] = sm[255];
}

// ---------------- scan the 196 block partials (one block) ----------------
__global__ __launch_bounds__(256) void k_scan_partials(const int* __restrict__ partials,
                                                       int* __restrict__ offs) {
    __shared__ int sm[256];
    int tid = threadIdx.x;
    int v = (tid < NB_SCAN) ? partials[tid] : 0;
    sm[tid] = v;
    __syncthreads();
    #pragma unroll
    for (int off = 1; off < 256; off <<= 1) {
        int t = (tid >= off) ? sm[tid - off] : 0;
        __syncthreads();
        sm[tid] += t;
        __syncthreads();
    }
    offs[tid] = sm[tid] - v;                       // exclusive
}

// ---------------- add block offsets; emit fill counters + dinv ----------------
__global__ __launch_bounds__(256) void k_scan_add(int* __restrict__ rowptr,
                                                  const int* __restrict__ offs,
                                                  int* __restrict__ fill,
                                                  const int* __restrict__ deg,
                                                  float* __restrict__ dinv) {
    int i = blockIdx.x * 256 + threadIdx.x;
    if (i < N_NODES) {
        int v = rowptr[i] + offs[blockIdx.x];
        rowptr[i] = v;
        fill[i] = v;
        dinv[i] = rsqrtf((float)(deg[i] + 1));     // +1 self loop
    }
    if (i == 0) rowptr[N_NODES] = N_EDGES;
}

// ---------------- CSR fill: col[pos] = src, bucketed by dst ----------------
__global__ __launch_bounds__(256) void k_fill(const int* __restrict__ ei,
                                              int* __restrict__ fill,
                                              int* __restrict__ col) {
    int e = blockIdx.x * 256 + threadIdx.x;
    if (e >= N_EDGES) return;
    int s = ei[e];
    int d = ei[N_EDGES + e];
    int pos = atomicAdd(&fill[d], 1);
    col[pos] = s;
}

// ---------------- GEMM: HS = (X @ W) * dinv[row] ----------------
// 256 threads, 64 rows/block in 2 passes of 32. W + 32 x-rows staged in LDS.
__global__ __launch_bounds__(256) void k_gemm_scale(
        const float* __restrict__ X, const float* __restrict__ W,
        const float* __restrict__ dinv, float* __restrict__ HS) {
    __shared__ float Wl[CH * CH];     // 64 KB
    __shared__ float xs[32][CH];      // 16 KB  -> 80 KB total, 2 blocks/CU

    const int tid = threadIdx.x;
    for (int i = tid; i < CH * CH; i += 256) Wl[i] = W[i];

    const int tc = tid & 31;    // col group: cols tc*4 .. tc*4+3
    const int tr = tid >> 5;    // row group: rows tr*4 .. tr*4+3 (within pass)
    const int row0 = blockIdx.x * 64;

    for (int pass = 0; pass < 2; ++pass) {
        const int rbase = row0 + pass * 32;
        __syncthreads();   // covers Wl load (pass 0) and xs reuse (pass 1)
        #pragma unroll
        for (int p = 0; p < 4; ++p) {
            int f = tid + p * 256;          // 0..1023 float4 slots
            int r = f >> 5, c = f & 31;
            int grow = rbase + r;
            float4 v = make_float4(0.f, 0.f, 0.f, 0.f);
            if (grow < N_NODES) v = *(const float4*)&X[grow * CH + c * 4];
            *(float4*)&xs[r][c * 4] = v;
        }
        __syncthreads();

        float4 acc0 = {0,0,0,0}, acc1 = {0,0,0,0}, acc2 = {0,0,0,0}, acc3 = {0,0,0,0};
        #pragma unroll
        for (int k4 = 0; k4 < 32; ++k4) {
            float4 x0 = *(const float4*)&xs[tr * 4 + 0][k4 * 4];
            float4 x1 = *(const float4*)&xs[tr * 4 + 1][k4 * 4];
            float4 x2 = *(const float4*)&xs[tr * 4 + 2][k4 * 4];
            float4 x3 = *(const float4*)&xs[tr * 4 + 3][k4 * 4];
            #pragma unroll
            for (int kk = 0; kk < 4; ++kk) {
                float4 w = *(const float4*)&Wl[(k4 * 4 + kk) * CH + tc * 4];
                float v0 = (&x0.x)[kk], v1 = (&x1.x)[kk], v2 = (&x2.x)[kk], v3 = (&x3.x)[kk];
                acc0.x += w.x * v0; acc0.y += w.y * v0; acc0.z += w.z * v0; acc0.w += w.w * v0;
                acc1.x += w.x * v1; acc1.y += w.y * v1; acc1.z += w.z * v1; acc1.w += w.w * v1;
                acc2.x += w.x * v2; acc2.y += w.y * v2; acc2.z += w.z * v2; acc2.w += w.w * v2;
                acc3.x += w.x * v3; acc3.y += w.y * v3; acc3.z += w.z * v3; acc3.w += w.w * v3;
            }
        }

        #pragma unroll
        for (int i = 0; i < 4; ++i) {
            int row = rbase + tr * 4 + i;
            if (row < N_NODES) {
                float di = dinv[row];
                float4 a = (i == 0) ? acc0 : (i == 1) ? acc1 : (i == 2) ? acc2 : acc3;
                *(float4*)&HS[row * CH + tc * 4] =
                    make_float4(a.x * di, a.y * di, a.z * di, a.w * di);
            }
        }
    }
}

// ---------------- aggregate: OUT[i] = relu(dinv[i]*(HS[i] + sum_{e in row i} HS[col[e]]) + b) ----------------
// 32 threads per node (one float4 per lane), 8 nodes per block. Pure gather, no atomics.
__global__ __launch_bounds__(256) void k_aggregate(
        const int* __restrict__ rowptr, const int* __restrict__ col,
        const float* __restrict__ HS, const float* __restrict__ dinv,
        const float* __restrict__ b, float* __restrict__ OUT) {
    int gid = blockIdx.x * 256 + threadIdx.x;
    int node = gid >> 5;
    if (node >= N_NODES) return;
    int c4 = (gid & 31) * 4;

    int e0 = rowptr[node];
    int e1 = rowptr[node + 1];

    float4 acc = *(const float4*)&HS[node * CH + c4];   // self loop term
    int e = e0;
    for (; e + 1 < e1; e += 2) {
        int sa = col[e];
        int sb = col[e + 1];
        float4 va = *(const float4*)&HS[sa * CH + c4];
        float4 vb = *(const float4*)&HS[sb * CH + c4];
        acc.x += va.x + vb.x;
        acc.y += va.y + vb.y;
        acc.z += va.z + vb.z;
        acc.w += va.w + vb.w;
    }
    if (e < e1) {
        int sa = col[e];
        float4 va = *(const float4*)&HS[sa * CH + c4];
        acc.x += va.x; acc.y += va.y; acc.z += va.z; acc.w += va.w;
    }

    float di = dinv[node];
    float4 bb = *(const float4*)&b[c4];
    float4 o;
    o.x = fmaxf(acc.x * di + bb.x, 0.f);
    o.y = fmaxf(acc.y * di + bb.y, 0.f);
    o.z = fmaxf(acc.z * di + bb.z, 0.f);
    o.w = fmaxf(acc.w * di + bb.w, 0.f);
    *(float4*)&OUT[node * CH + c4] = o;
}

extern "C" void kernel_launch(void* const* d_in, const int* in_sizes, int n_in,
                              void* d_out, int out_size, void* d_ws, size_t ws_size,
                              hipStream_t stream) {
    const float* x  = (const float*)d_in[0];
    const int*   ei = (const int*)d_in[1];
    const float* W1 = (const float*)d_in[2];
    const float* b1 = (const float*)d_in[3];
    const float* W2 = (const float*)d_in[4];
    const float* b2 = (const float*)d_in[5];
    float* out = (float*)d_out;

    // workspace layout (4B elems):
    int*   deg      = (int*)d_ws;              // 50176
    int*   rowptr   = deg + 50176;             // 50176 (uses [0..N_NODES])
    int*   fillc    = rowptr + 50176;          // 50176
    int*   partials = fillc + 50176;           // 256
    int*   offs     = partials + 256;          // 256
    int*   col      = offs + 256;              // 800256
    float* dinv     = (float*)(col + 800256);  // 50176
    float* hs       = dinv + 50176;            // N*CH = 6.4M floats

    const int gN  = (N_NODES + 255) / 256;             // 196
    const int gE  = (N_EDGES + 255) / 256;             // 3125
    const int gG  = (N_NODES + 63) / 64;               // 782
    const int gA  = (N_NODES * 32 + 255) / 256;        // 6250

    // ---- CSR build (by dst) + dinv ----
    k_zero<<<gN, 256, 0, stream>>>(deg, 50176);
    k_hist<<<gE, 256, 0, stream>>>(ei + N_EDGES, deg);
    k_scan_block<<<NB_SCAN, 256, 0, stream>>>(deg, rowptr, partials);
    k_scan_partials<<<1, 256, 0, stream>>>(partials, offs);
    k_scan_add<<<NB_SCAN, 256, 0, stream>>>(rowptr, offs, fillc, deg, dinv);
    k_fill<<<gE, 256, 0, stream>>>(ei, fillc, col);

    // ---- layer 1 ----
    k_gemm_scale<<<gG, 256, 0, stream>>>(x, W1, dinv, hs);
    k_aggregate<<<gA, 256, 0, stream>>>(rowptr, col, hs, dinv, b1, out);

    // ---- layer 2 ----
    k_gemm_scale<<<gG, 256, 0, stream>>>(out, W2, dinv, hs);
    k_aggregate<<<gA, 256, 0, stream>>>(rowptr, col, hs, dinv, b2, out);
}

// Round 3
// 285.602 us; speedup vs baseline: 13.1676x; 4.3843x over previous
//
#include <hip/hip_runtime.h>

#define N_NODES 50000
#define N_EDGES 800000
#define CH 128
#define NB_SCAN 196   // ceil(N_NODES/256)

// ---------------- zero int degree array ----------------
__global__ __launch_bounds__(256) void k_zero(int* p, int n) {
    int i = blockIdx.x * 256 + threadIdx.x;
    if (i < n) p[i] = 0;
}

// ---------------- histogram of dst (in-degree, no self loop) ----------------
__global__ __launch_bounds__(256) void k_hist(const int* __restrict__ dst,
                                              int* __restrict__ deg) {
    int e = blockIdx.x * 256 + threadIdx.x;
    if (e < N_EDGES) atomicAdd(&deg[dst[e]], 1);
}

// ---------------- block-wise scan ----------------
__global__ __launch_bounds__(256) void k_scan_block(const int* __restrict__ deg,
                                                    int* __restrict__ rowptr,
                                                    int* __restrict__ partials) {
    __shared__ int sm[256];
    int tid = threadIdx.x;
    int i = blockIdx.x * 256 + tid;
    int v = (i < N_NODES) ? deg[i] : 0;
    sm[tid] = v;
    __syncthreads();
    #pragma unroll
    for (int off = 1; off < 256; off <<= 1) {
        int t = (tid >= off) ? sm[tid - off] : 0;
        __syncthreads();
        sm[tid] += t;
        __syncthreads();
    }
    if (i < N_NODES) rowptr[i] = sm[tid] - v;     // exclusive within block
    if (tid == 255) partials[blockIdx.x] = sm[255];
}

__global__ __launch_bounds__(256) void k_scan_partials(const int* __restrict__ partials,
                                                       int* __restrict__ offs) {
    __shared__ int sm[256];
    int tid = threadIdx.x;
    int v = (tid < NB_SCAN) ? partials[tid] : 0;
    sm[tid] = v;
    __syncthreads();
    #pragma unroll
    for (int off = 1; off < 256; off <<= 1) {
        int t = (tid >= off) ? sm[tid - off] : 0;
        __syncthreads();
        sm[tid] += t;
        __syncthreads();
    }
    offs[tid] = sm[tid] - v;                       // exclusive
}

__global__ __launch_bounds__(256) void k_scan_add(int* __restrict__ rowptr,
                                                  const int* __restrict__ offs,
                                                  int* __restrict__ fill,
                                                  const int* __restrict__ deg,
                                                  float* __restrict__ dinv) {
    int i = blockIdx.x * 256 + threadIdx.x;
    if (i < N_NODES) {
        int v = rowptr[i] + offs[blockIdx.x];
        rowptr[i] = v;
        fill[i] = v;
        dinv[i] = rsqrtf((float)(deg[i] + 1));     // +1 self loop
    }
    if (i == 0) rowptr[N_NODES] = N_EDGES;
}

// ---------------- CSR fill: col[pos] = src, bucketed by dst ----------------
__global__ __launch_bounds__(256) void k_fill(const int* __restrict__ ei,
                                              int* __restrict__ fill,
                                              int* __restrict__ col) {
    int e = blockIdx.x * 256 + threadIdx.x;
    if (e >= N_EDGES) return;
    int s = ei[e];
    int d = ei[N_EDGES + e];
    int pos = atomicAdd(&fill[d], 1);
    col[pos] = s;
}

// ---------------- GEMM: HS = (X @ W) * dinv[row] ----------------
// 256 threads, 32 rows/block. Only X tile staged in LDS (16 KB -> high occupancy).
// W read straight from L1/L2 (64 KB, resident; per-k row is a coalesced 512B slice
// shared by both half-waves). Per-thread 4 rows x 4 cols, acc[4][4] = 16 VGPRs.
// Unroll kept small to avoid the 256-VGPR spill seen in round 2.
__global__ __launch_bounds__(256) void k_gemm_scale(
        const float* __restrict__ X, const float* __restrict__ W,
        const float* __restrict__ dinv, float* __restrict__ HS) {
    __shared__ float xs[32][CH];      // 16 KB

    const int tid = threadIdx.x;
    const int tc = tid & 31;    // col group: cols tc*4 .. tc*4+3
    const int tr = tid >> 5;    // row group: rows tr*4 .. tr*4+3
    const int row0 = blockIdx.x * 32;

    // stage 32 X rows: 1024 float4 slots / 256 threads = 4 each
    #pragma unroll
    for (int p = 0; p < 4; ++p) {
        int f = tid + p * 256;
        int r = f >> 5, c = f & 31;
        int grow = row0 + r;
        float4 v = make_float4(0.f, 0.f, 0.f, 0.f);
        if (grow < N_NODES) v = *(const float4*)&X[grow * CH + c * 4];
        *(float4*)&xs[r][c * 4] = v;
    }
    __syncthreads();

    float acc[4][4] = {};
    const float* wp = W + tc * 4;

    #pragma unroll 2
    for (int k4 = 0; k4 < 32; ++k4) {
        float4 xq[4];
        #pragma unroll
        for (int r = 0; r < 4; ++r)
            xq[r] = *(const float4*)&xs[tr * 4 + r][k4 * 4];   // broadcast within tc-group
        #pragma unroll
        for (int kk = 0; kk < 4; ++kk) {
            float4 w = *(const float4*)&wp[(k4 * 4 + kk) * CH];
            #pragma unroll
            for (int r = 0; r < 4; ++r) {
                float xv = (&xq[r].x)[kk];
                acc[r][0] += w.x * xv;
                acc[r][1] += w.y * xv;
                acc[r][2] += w.z * xv;
                acc[r][3] += w.w * xv;
            }
        }
    }

    #pragma unroll
    for (int r = 0; r < 4; ++r) {
        int row = row0 + tr * 4 + r;
        if (row < N_NODES) {
            float di = dinv[row];
            *(float4*)&HS[row * CH + tc * 4] = make_float4(
                acc[r][0] * di, acc[r][1] * di, acc[r][2] * di, acc[r][3] * di);
        }
    }
}

// ---------------- aggregate: OUT[i] = relu(dinv[i]*(HS[i] + sum_{e in row i} HS[col[e]]) + b) ----------------
__global__ __launch_bounds__(256) void k_aggregate(
        const int* __restrict__ rowptr, const int* __restrict__ col,
        const float* __restrict__ HS, const float* __restrict__ dinv,
        const float* __restrict__ b, float* __restrict__ OUT) {
    int gid = blockIdx.x * 256 + threadIdx.x;
    int node = gid >> 5;
    if (node >= N_NODES) return;
    int c4 = (gid & 31) * 4;

    int e0 = rowptr[node];
    int e1 = rowptr[node + 1];

    float4 acc = *(const float4*)&HS[node * CH + c4];   // self loop term
    int e = e0;
    for (; e + 1 < e1; e += 2) {
        int sa = col[e];
        int sb = col[e + 1];
        float4 va = *(const float4*)&HS[sa * CH + c4];
        float4 vb = *(const float4*)&HS[sb * CH + c4];
        acc.x += va.x + vb.x;
        acc.y += va.y + vb.y;
        acc.z += va.z + vb.z;
        acc.w += va.w + vb.w;
    }
    if (e < e1) {
        int sa = col[e];
        float4 va = *(const float4*)&HS[sa * CH + c4];
        acc.x += va.x; acc.y += va.y; acc.z += va.z; acc.w += va.w;
    }

    float di = dinv[node];
    float4 bb = *(const float4*)&b[c4];
    float4 o;
    o.x = fmaxf(acc.x * di + bb.x, 0.f);
    o.y = fmaxf(acc.y * di + bb.y, 0.f);
    o.z = fmaxf(acc.z * di + bb.z, 0.f);
    o.w = fmaxf(acc.w * di + bb.w, 0.f);
    *(float4*)&OUT[node * CH + c4] = o;
}

extern "C" void kernel_launch(void* const* d_in, const int* in_sizes, int n_in,
                              void* d_out, int out_size, void* d_ws, size_t ws_size,
                              hipStream_t stream) {
    const float* x  = (const float*)d_in[0];
    const int*   ei = (const int*)d_in[1];
    const float* W1 = (const float*)d_in[2];
    const float* b1 = (const float*)d_in[3];
    const float* W2 = (const float*)d_in[4];
    const float* b2 = (const float*)d_in[5];
    float* out = (float*)d_out;

    // workspace layout (4B elems):
    int*   deg      = (int*)d_ws;              // 50176
    int*   rowptr   = deg + 50176;             // 50176 (uses [0..N_NODES])
    int*   fillc    = rowptr + 50176;          // 50176
    int*   partials = fillc + 50176;           // 256
    int*   offs     = partials + 256;          // 256
    int*   col      = offs + 256;              // 800256
    float* dinv     = (float*)(col + 800256);  // 50176
    float* hs       = dinv + 50176;            // N*CH = 6.4M floats

    const int gN  = (N_NODES + 255) / 256;             // 196
    const int gE  = (N_EDGES + 255) / 256;             // 3125
    const int gG  = (N_NODES + 31) / 32;               // 1563
    const int gA  = (N_NODES * 32 + 255) / 256;        // 6250

    // ---- CSR build (by dst) + dinv ----
    k_zero<<<gN, 256, 0, stream>>>(deg, 50176);
    k_hist<<<gE, 256, 0, stream>>>(ei + N_EDGES, deg);
    k_scan_block<<<NB_SCAN, 256, 0, stream>>>(deg, rowptr, partials);
    k_scan_partials<<<1, 256, 0, stream>>>(partials, offs);
    k_scan_add<<<NB_SCAN, 256, 0, stream>>>(rowptr, offs, fillc, deg, dinv);
    k_fill<<<gE, 256, 0, stream>>>(ei, fillc, col);

    // ---- layer 1 ----
    k_gemm_scale<<<gG, 256, 0, stream>>>(x, W1, dinv, hs);
    k_aggregate<<<gA, 256, 0, stream>>>(rowptr, col, hs, dinv, b1, out);

    // ---- layer 2 ----
    k_gemm_scale<<<gG, 256, 0, stream>>>(out, W2, dinv, hs);
    k_aggregate<<<gA, 256, 0, stream>>>(rowptr, col, hs, dinv, b2, out);
}

// Round 4
// 242.349 us; speedup vs baseline: 15.5176x; 1.1785x over previous
//
#include <hip/hip_runtime.h>

#define N_NODES 50000
#define N_EDGES 800000
#define CH 128
#define NB_SCAN 196   // ceil(N_NODES/256)

__device__ __forceinline__ float bf2f(unsigned short u) {
    union { unsigned int i; float f; } c;
    c.i = ((unsigned int)u) << 16;
    return c.f;
}
__device__ __forceinline__ unsigned short f2bf(float f) {
    union { float f; unsigned int i; } c;
    c.f = f;
    unsigned int lsb = (c.i >> 16) & 1u;
    c.i += 0x7fffu + lsb;          // round-to-nearest-even
    return (unsigned short)(c.i >> 16);
}

// ---------------- zero int degree array ----------------
__global__ __launch_bounds__(256) void k_zero(int* p, int n) {
    int i = blockIdx.x * 256 + threadIdx.x;
    if (i < n) p[i] = 0;
}

// ---------------- histogram of dst (in-degree, no self loop) ----------------
__global__ __launch_bounds__(256) void k_hist(const int* __restrict__ dst,
                                              int* __restrict__ deg) {
    int e = blockIdx.x * 256 + threadIdx.x;
    if (e < N_EDGES) atomicAdd(&deg[dst[e]], 1);
}

// ---------------- block-wise scan ----------------
__global__ __launch_bounds__(256) void k_scan_block(const int* __restrict__ deg,
                                                    int* __restrict__ rowptr,
                                                    int* __restrict__ partials) {
    __shared__ int sm[256];
    int tid = threadIdx.x;
    int i = blockIdx.x * 256 + tid;
    int v = (i < N_NODES) ? deg[i] : 0;
    sm[tid] = v;
    __syncthreads();
    #pragma unroll
    for (int off = 1; off < 256; off <<= 1) {
        int t = (tid >= off) ? sm[tid - off] : 0;
        __syncthreads();
        sm[tid] += t;
        __syncthreads();
    }
    if (i < N_NODES) rowptr[i] = sm[tid] - v;     // exclusive within block
    if (tid == 255) partials[blockIdx.x] = sm[255];
}

__global__ __launch_bounds__(256) void k_scan_partials(const int* __restrict__ partials,
                                                       int* __restrict__ offs) {
    __shared__ int sm[256];
    int tid = threadIdx.x;
    int v = (tid < NB_SCAN) ? partials[tid] : 0;
    sm[tid] = v;
    __syncthreads();
    #pragma unroll
    for (int off = 1; off < 256; off <<= 1) {
        int t = (tid >= off) ? sm[tid - off] : 0;
        __syncthreads();
        sm[tid] += t;
        __syncthreads();
    }
    offs[tid] = sm[tid] - v;                       // exclusive
}

__global__ __launch_bounds__(256) void k_scan_add(int* __restrict__ rowptr,
                                                  const int* __restrict__ offs,
                                                  int* __restrict__ fill,
                                                  const int* __restrict__ deg,
                                                  float* __restrict__ dinv) {
    int i = blockIdx.x * 256 + threadIdx.x;
    if (i < N_NODES) {
        int v = rowptr[i] + offs[blockIdx.x];
        rowptr[i] = v;
        fill[i] = v;
        dinv[i] = rsqrtf((float)(deg[i] + 1));     // +1 self loop
    }
    if (i == 0) rowptr[N_NODES] = N_EDGES;
}

// ---------------- CSR fill: col[pos] = src, bucketed by dst ----------------
__global__ __launch_bounds__(256) void k_fill(const int* __restrict__ ei,
                                              int* __restrict__ fill,
                                              int* __restrict__ col) {
    int e = blockIdx.x * 256 + threadIdx.x;
    if (e >= N_EDGES) return;
    int s = ei[e];
    int d = ei[N_EDGES + e];
    int pos = atomicAdd(&fill[d], 1);
    col[pos] = s;
}

// ---------------- GEMM: HS(bf16) = (X @ W) * dinv[row] ----------------
// 256 threads, 32 rows/block. X tile in LDS (16 KB). W straight from L1/L2.
// Per-thread 4 rows x 4 cols, acc[4][4]. Output converted to bf16 (ushort4 store).
__global__ __launch_bounds__(256) void k_gemm_scale(
        const float* __restrict__ X, const float* __restrict__ W,
        const float* __restrict__ dinv, unsigned short* __restrict__ HS) {
    __shared__ float xs[32][CH];      // 16 KB

    const int tid = threadIdx.x;
    const int tc = tid & 31;    // col group: cols tc*4 .. tc*4+3
    const int tr = tid >> 5;    // row group: rows tr*4 .. tr*4+3
    const int row0 = blockIdx.x * 32;

    #pragma unroll
    for (int p = 0; p < 4; ++p) {
        int f = tid + p * 256;
        int r = f >> 5, c = f & 31;
        int grow = row0 + r;
        float4 v = make_float4(0.f, 0.f, 0.f, 0.f);
        if (grow < N_NODES) v = *(const float4*)&X[grow * CH + c * 4];
        *(float4*)&xs[r][c * 4] = v;
    }
    __syncthreads();

    float acc[4][4] = {};
    const float* wp = W + tc * 4;

    #pragma unroll 2
    for (int k4 = 0; k4 < 32; ++k4) {
        float4 xq[4];
        #pragma unroll
        for (int r = 0; r < 4; ++r)
            xq[r] = *(const float4*)&xs[tr * 4 + r][k4 * 4];   // broadcast within tc-group
        #pragma unroll
        for (int kk = 0; kk < 4; ++kk) {
            float4 w = *(const float4*)&wp[(k4 * 4 + kk) * CH];
            #pragma unroll
            for (int r = 0; r < 4; ++r) {
                float xv = (&xq[r].x)[kk];
                acc[r][0] += w.x * xv;
                acc[r][1] += w.y * xv;
                acc[r][2] += w.z * xv;
                acc[r][3] += w.w * xv;
            }
        }
    }

    #pragma unroll
    for (int r = 0; r < 4; ++r) {
        int row = row0 + tr * 4 + r;
        if (row < N_NODES) {
            float di = dinv[row];
            ushort4 o;
            o.x = f2bf(acc[r][0] * di);
            o.y = f2bf(acc[r][1] * di);
            o.z = f2bf(acc[r][2] * di);
            o.w = f2bf(acc[r][3] * di);
            *(ushort4*)&HS[row * CH + tc * 4] = o;
        }
    }
}

// ---------------- aggregate: OUT = relu(dinv*(HS[self] + sum HS[col]) + b), HS in bf16 ----------------
// 32 lanes per node, one ushort4 (4 channels) per lane. f32 accumulate. No atomics.
__global__ __launch_bounds__(256) void k_aggregate(
        const int* __restrict__ rowptr, const int* __restrict__ col,
        const unsigned short* __restrict__ HS, const float* __restrict__ dinv,
        const float* __restrict__ b, float* __restrict__ OUT) {
    int gid = blockIdx.x * 256 + threadIdx.x;
    int node = gid >> 5;
    if (node >= N_NODES) return;
    int lane = gid & 31;
    const ushort4* H4 = (const ushort4*)HS;    // 32 ushort4 per row

    int e0 = rowptr[node];
    int e1 = rowptr[node + 1];

    ushort4 hself = H4[node * 32 + lane];
    float ax = bf2f(hself.x), ay = bf2f(hself.y), az = bf2f(hself.z), aw = bf2f(hself.w);

    int e = e0;
    for (; e + 1 < e1; e += 2) {
        int sa = col[e];
        int sb = col[e + 1];
        ushort4 va = H4[sa * 32 + lane];
        ushort4 vb = H4[sb * 32 + lane];
        ax += bf2f(va.x) + bf2f(vb.x);
        ay += bf2f(va.y) + bf2f(vb.y);
        az += bf2f(va.z) + bf2f(vb.z);
        aw += bf2f(va.w) + bf2f(vb.w);
    }
    if (e < e1) {
        ushort4 va = H4[col[e] * 32 + lane];
        ax += bf2f(va.x); ay += bf2f(va.y); az += bf2f(va.z); aw += bf2f(va.w);
    }

    float di = dinv[node];
    float4 bb = *(const float4*)&b[lane * 4];
    float4 o;
    o.x = fmaxf(ax * di + bb.x, 0.f);
    o.y = fmaxf(ay * di + bb.y, 0.f);
    o.z = fmaxf(az * di + bb.z, 0.f);
    o.w = fmaxf(aw * di + bb.w, 0.f);
    *(float4*)&OUT[node * CH + lane * 4] = o;
}

extern "C" void kernel_launch(void* const* d_in, const int* in_sizes, int n_in,
                              void* d_out, int out_size, void* d_ws, size_t ws_size,
                              hipStream_t stream) {
    const float* x  = (const float*)d_in[0];
    const int*   ei = (const int*)d_in[1];
    const float* W1 = (const float*)d_in[2];
    const float* b1 = (const float*)d_in[3];
    const float* W2 = (const float*)d_in[4];
    const float* b2 = (const float*)d_in[5];
    float* out = (float*)d_out;

    // workspace layout (4B units unless noted):
    int*   deg      = (int*)d_ws;              // 50176
    int*   rowptr   = deg + 50176;             // 50176 (uses [0..N_NODES])
    int*   fillc    = rowptr + 50176;          // 50176
    int*   partials = fillc + 50176;           // 256
    int*   offs     = partials + 256;          // 256
    int*   col      = offs + 256;              // 800256
    float* dinv     = (float*)(col + 800256);  // 50176
    unsigned short* hs = (unsigned short*)(dinv + 50176);  // N*CH bf16 = 12.8 MB

    const int gN  = (N_NODES + 255) / 256;             // 196
    const int gE  = (N_EDGES + 255) / 256;             // 3125
    const int gG  = (N_NODES + 31) / 32;               // 1563
    const int gA  = (N_NODES * 32 + 255) / 256;        // 6250

    // ---- CSR build (by dst) + dinv ----
    k_zero<<<gN, 256, 0, stream>>>(deg, 50176);
    k_hist<<<gE, 256, 0, stream>>>(ei + N_EDGES, deg);
    k_scan_block<<<NB_SCAN, 256, 0, stream>>>(deg, rowptr, partials);
    k_scan_partials<<<1, 256, 0, stream>>>(partials, offs);
    k_scan_add<<<NB_SCAN, 256, 0, stream>>>(rowptr, offs, fillc, deg, dinv);
    k_fill<<<gE, 256, 0, stream>>>(ei, fillc, col);

    // ---- layer 1 ----
    k_gemm_scale<<<gG, 256, 0, stream>>>(x, W1, dinv, hs);
    k_aggregate<<<gA, 256, 0, stream>>>(rowptr, col, hs, dinv, b1, out);

    // ---- layer 2 ----
    k_gemm_scale<<<gG, 256, 0, stream>>>(out, W2, dinv, hs);
    k_aggregate<<<gA, 256, 0, stream>>>(rowptr, col, hs, dinv, b2, out);
}

// Round 5
// 186.857 us; speedup vs baseline: 20.1260x; 1.2970x over previous
//
#include <hip/hip_runtime.h>

#define N_NODES 50000
#define N_EDGES 800000
#define CH 128
#define NBUCK 196          // ceil(50000/256): buckets of 256 dst nodes
#define B_BIN 250          // bin-pass blocks
#define CHUNK 3200         // edges per bin-pass block (250*3200 = 800000)

__device__ __forceinline__ float bf2f(unsigned short u) {
    union { unsigned int i; float f; } c;
    c.i = ((unsigned int)u) << 16;
    return c.f;
}
__device__ __forceinline__ unsigned short f2bf(float f) {
    union { float f; unsigned int i; } c;
    c.f = f;
    unsigned int lsb = (c.i >> 16) & 1u;
    c.i += 0x7fffu + lsb;          // round-to-nearest-even
    return (unsigned short)(c.i >> 16);
}

// ---------------- pass A1: per-block bucket histogram + range reservation ----------------
__global__ __launch_bounds__(256) void k_bin_count(const int* __restrict__ dst,
                                                   int* __restrict__ bucket_cnt,
                                                   int* __restrict__ blk_base) {
    __shared__ int h[NBUCK];
    const int tid = threadIdx.x, b = blockIdx.x;
    for (int i = tid; i < NBUCK; i += 256) h[i] = 0;
    __syncthreads();
    const int e0 = b * CHUNK;
    for (int i = tid; i < CHUNK; i += 256)
        atomicAdd(&h[dst[e0 + i] >> 8], 1);
    __syncthreads();
    for (int k = tid; k < NBUCK; k += 256) {
        int c = h[k];
        blk_base[b * NBUCK + k] = c ? atomicAdd(&bucket_cnt[k], c) : 0;
    }
}

// ---------------- scan 196 bucket counts (1 block) ----------------
__global__ __launch_bounds__(256) void k_scan_buckets(const int* __restrict__ bucket_cnt,
                                                      int* __restrict__ bucket_base) {
    __shared__ int sm[256];
    const int tid = threadIdx.x;
    int v = (tid < NBUCK) ? bucket_cnt[tid] : 0;
    sm[tid] = v;
    __syncthreads();
    #pragma unroll
    for (int off = 1; off < 256; off <<= 1) {
        int t = (tid >= off) ? sm[tid - off] : 0;
        __syncthreads();
        sm[tid] += t;
        __syncthreads();
    }
    if (tid < NBUCK) bucket_base[tid] = sm[tid] - v;   // exclusive
    if (tid == 0) bucket_base[NBUCK] = N_EDGES;
}

// ---------------- pass A2: place packed edges into bucket-contiguous ebuf ----------------
__global__ __launch_bounds__(256) void k_bin_place(const int* __restrict__ ei,
                                                   const int* __restrict__ bucket_base,
                                                   const int* __restrict__ blk_base,
                                                   unsigned int* __restrict__ ebuf) {
    __shared__ int h[NBUCK];
    const int tid = threadIdx.x, b = blockIdx.x;
    for (int i = tid; i < NBUCK; i += 256) h[i] = 0;
    __syncthreads();
    const int e0 = b * CHUNK;
    for (int i = tid; i < CHUNK; i += 256) {
        int s = ei[e0 + i];
        int d = ei[N_EDGES + e0 + i];
        int k = d >> 8;
        int loc = atomicAdd(&h[k], 1);
        int pos = bucket_base[k] + blk_base[b * NBUCK + k] + loc;
        ebuf[pos] = ((unsigned int)s << 8) | (unsigned int)(d & 255);
    }
}

// ---------------- pass B: per-bucket exact CSR (rowptr, col, dinv) ----------------
__global__ __launch_bounds__(256) void k_bucket_csr(const unsigned int* __restrict__ ebuf,
                                                    const int* __restrict__ bucket_base,
                                                    int* __restrict__ rowptr,
                                                    int* __restrict__ col,
                                                    float* __restrict__ dinv) {
    __shared__ int cnts[256];
    __shared__ int fillc[256];
    __shared__ int sm[256];
    const int tid = threadIdx.x, k = blockIdx.x;
    const int node0 = k << 8;
    const int e0 = bucket_base[k], e1 = bucket_base[k + 1];
    const int cnt = e1 - e0;

    cnts[tid] = 0;
    __syncthreads();
    for (int i = tid; i < cnt; i += 256)
        atomicAdd(&cnts[ebuf[e0 + i] & 255], 1);
    __syncthreads();

    int v = cnts[tid];
    sm[tid] = v;
    __syncthreads();
    #pragma unroll
    for (int off = 1; off < 256; off <<= 1) {
        int t = (tid >= off) ? sm[tid - off] : 0;
        __syncthreads();
        sm[tid] += t;
        __syncthreads();
    }
    int rp = sm[tid] - v;              // exclusive prefix within bucket
    fillc[tid] = rp;
    int node = node0 + tid;
    if (node < N_NODES) {
        rowptr[node] = e0 + rp;
        dinv[node] = rsqrtf((float)(v + 1));   // +1 self loop
    }
    if (k == NBUCK - 1 && tid == 0) rowptr[N_NODES] = N_EDGES;
    __syncthreads();

    for (int i = tid; i < cnt; i += 256) {
        unsigned int pv = ebuf[e0 + i];
        int j = pv & 255;
        int loc = atomicAdd(&fillc[j], 1);
        col[e0 + loc] = (int)(pv >> 8);        // writes stay in this bucket's 16 KB window
    }
}

// ---------------- GEMM: HS(bf16) = (X @ W) * dinv[row] ----------------
// 256 threads, 32 rows/block. X tile in LDS (16 KB). W straight from L1/L2.
__global__ __launch_bounds__(256) void k_gemm_scale(
        const float* __restrict__ X, const float* __restrict__ W,
        const float* __restrict__ dinv, unsigned short* __restrict__ HS) {
    __shared__ float xs[32][CH];      // 16 KB

    const int tid = threadIdx.x;
    const int tc = tid & 31;    // cols tc*4 .. tc*4+3
    const int tr = tid >> 5;    // rows tr*4 .. tr*4+3
    const int row0 = blockIdx.x * 32;

    #pragma unroll
    for (int p = 0; p < 4; ++p) {
        int f = tid + p * 256;
        int r = f >> 5, c = f & 31;
        int grow = row0 + r;
        float4 v = make_float4(0.f, 0.f, 0.f, 0.f);
        if (grow < N_NODES) v = *(const float4*)&X[grow * CH + c * 4];
        *(float4*)&xs[r][c * 4] = v;
    }
    __syncthreads();

    float acc[4][4] = {};
    const float* wp = W + tc * 4;

    #pragma unroll 2
    for (int k4 = 0; k4 < 32; ++k4) {
        float4 xq[4];
        #pragma unroll
        for (int r = 0; r < 4; ++r)
            xq[r] = *(const float4*)&xs[tr * 4 + r][k4 * 4];   // broadcast within tc-group
        #pragma unroll
        for (int kk = 0; kk < 4; ++kk) {
            float4 w = *(const float4*)&wp[(k4 * 4 + kk) * CH];
            #pragma unroll
            for (int r = 0; r < 4; ++r) {
                float xv = (&xq[r].x)[kk];
                acc[r][0] += w.x * xv;
                acc[r][1] += w.y * xv;
                acc[r][2] += w.z * xv;
                acc[r][3] += w.w * xv;
            }
        }
    }

    #pragma unroll
    for (int r = 0; r < 4; ++r) {
        int row = row0 + tr * 4 + r;
        if (row < N_NODES) {
            float di = dinv[row];
            ushort4 o;
            o.x = f2bf(acc[r][0] * di);
            o.y = f2bf(acc[r][1] * di);
            o.z = f2bf(acc[r][2] * di);
            o.w = f2bf(acc[r][3] * di);
            *(ushort4*)&HS[row * CH + tc * 4] = o;
        }
    }
}

// ---------------- aggregate: OUT = relu(dinv*(HS[self] + sum HS[col]) + b), HS in bf16 ----------------
__global__ __launch_bounds__(256) void k_aggregate(
        const int* __restrict__ rowptr, const int* __restrict__ col,
        const unsigned short* __restrict__ HS, const float* __restrict__ dinv,
        const float* __restrict__ b, float* __restrict__ OUT) {
    int gid = blockIdx.x * 256 + threadIdx.x;
    int node = gid >> 5;
    if (node >= N_NODES) return;
    int lane = gid & 31;
    const ushort4* H4 = (const ushort4*)HS;    // 32 ushort4 per row

    int e0 = rowptr[node];
    int e1 = rowptr[node + 1];

    ushort4 hself = H4[node * 32 + lane];
    float ax = bf2f(hself.x), ay = bf2f(hself.y), az = bf2f(hself.z), aw = bf2f(hself.w);

    int e = e0;
    for (; e + 1 < e1; e += 2) {
        int sa = col[e];
        int sb = col[e + 1];
        ushort4 va = H4[sa * 32 + lane];
        ushort4 vb = H4[sb * 32 + lane];
        ax += bf2f(va.x) + bf2f(vb.x);
        ay += bf2f(va.y) + bf2f(vb.y);
        az += bf2f(va.z) + bf2f(vb.z);
        aw += bf2f(va.w) + bf2f(vb.w);
    }
    if (e < e1) {
        ushort4 va = H4[col[e] * 32 + lane];
        ax += bf2f(va.x); ay += bf2f(va.y); az += bf2f(va.z); aw += bf2f(va.w);
    }

    float di = dinv[node];
    float4 bb = *(const float4*)&b[lane * 4];
    float4 o;
    o.x = fmaxf(ax * di + bb.x, 0.f);
    o.y = fmaxf(ay * di + bb.y, 0.f);
    o.z = fmaxf(az * di + bb.z, 0.f);
    o.w = fmaxf(aw * di + bb.w, 0.f);
    *(float4*)&OUT[node * CH + lane * 4] = o;
}

extern "C" void kernel_launch(void* const* d_in, const int* in_sizes, int n_in,
                              void* d_out, int out_size, void* d_ws, size_t ws_size,
                              hipStream_t stream) {
    const float* x  = (const float*)d_in[0];
    const int*   ei = (const int*)d_in[1];
    const float* W1 = (const float*)d_in[2];
    const float* b1 = (const float*)d_in[3];
    const float* W2 = (const float*)d_in[4];
    const float* b2 = (const float*)d_in[5];
    float* out = (float*)d_out;

    // workspace layout (4B units):
    int* bucket_cnt  = (int*)d_ws;               // 256
    int* bucket_base = bucket_cnt + 256;         // 256 (uses NBUCK+1)
    int* blk_base    = bucket_base + 256;        // 250*196 = 49000 -> pad 49152
    unsigned int* ebuf = (unsigned int*)(blk_base + 49152);  // 800000 -> pad 800256
    int* rowptr      = (int*)(ebuf + 800256);    // 50001 -> pad 50176
    int* col         = rowptr + 50176;           // 800000 -> pad 800256
    float* dinv      = (float*)(col + 800256);   // 50000 -> pad 50176
    unsigned short* hs = (unsigned short*)(dinv + 50176);    // N*CH bf16 = 12.8 MB

    const int gG = (N_NODES + 31) / 32;              // 1563
    const int gA = (N_NODES * 32 + 255) / 256;       // 6250

    // ---- CSR build: two-level counting sort ----
    hipMemsetAsync(bucket_cnt, 0, NBUCK * sizeof(int), stream);
    k_bin_count<<<B_BIN, 256, 0, stream>>>(ei + N_EDGES, bucket_cnt, blk_base);
    k_scan_buckets<<<1, 256, 0, stream>>>(bucket_cnt, bucket_base);
    k_bin_place<<<B_BIN, 256, 0, stream>>>(ei, bucket_base, blk_base, ebuf);
    k_bucket_csr<<<NBUCK, 256, 0, stream>>>(ebuf, bucket_base, rowptr, col, dinv);

    // ---- layer 1 ----
    k_gemm_scale<<<gG, 256, 0, stream>>>(x, W1, dinv, hs);
    k_aggregate<<<gA, 256, 0, stream>>>(rowptr, col, hs, dinv, b1, out);

    // ---- layer 2 ----
    k_gemm_scale<<<gG, 256, 0, stream>>>(out, W2, dinv, hs);
    k_aggregate<<<gA, 256, 0, stream>>>(rowptr, col, hs, dinv, b2, out);
}

// Round 6
// 160.391 us; speedup vs baseline: 23.4470x; 1.1650x over previous
//
#include <hip/hip_runtime.h>

#define N_NODES 50000
#define N_EDGES 800000
#define CH 128
#define NBUCK 196          // ceil(50000/256): buckets of 256 dst nodes
#define B_BIN 250          // bin-pass blocks
#define CHUNK 3200         // edges per bin-pass block (250*3200 = 800000)

typedef __attribute__((ext_vector_type(8))) short bf16x8;
typedef __attribute__((ext_vector_type(4))) float f32x4;

__device__ __forceinline__ float bf2f(unsigned short u) {
    union { unsigned int i; float f; } c;
    c.i = ((unsigned int)u) << 16;
    return c.f;
}
__device__ __forceinline__ unsigned short f2bf(float f) {
    union { float f; unsigned int i; } c;
    c.f = f;
    unsigned int lsb = (c.i >> 16) & 1u;
    c.i += 0x7fffu + lsb;          // round-to-nearest-even
    return (unsigned short)(c.i >> 16);
}

// ---------------- pass A1: per-block bucket histogram (no global atomics) ----------------
__global__ __launch_bounds__(256) void k_bin_count(const int* __restrict__ dst,
                                                   int* __restrict__ blk_base) {
    __shared__ int h[NBUCK];
    const int tid = threadIdx.x, b = blockIdx.x;
    for (int i = tid; i < NBUCK; i += 256) h[i] = 0;
    __syncthreads();
    const int e0 = b * CHUNK;
    for (int i = tid; i < CHUNK; i += 256)
        atomicAdd(&h[dst[e0 + i] >> 8], 1);
    __syncthreads();
    for (int k = tid; k < NBUCK; k += 256)
        blk_base[b * NBUCK + k] = h[k];
}

// ---------------- column scan: per bucket k, exclusive-scan counts over the 250 blocks ----------------
__global__ __launch_bounds__(256) void k_colscan(int* __restrict__ blk_base,
                                                 int* __restrict__ bucket_cnt) {
    __shared__ int sm[256];
    const int tid = threadIdx.x, k = blockIdx.x;
    int v = (tid < B_BIN) ? blk_base[tid * NBUCK + k] : 0;
    sm[tid] = v;
    __syncthreads();
    #pragma unroll
    for (int off = 1; off < 256; off <<= 1) {
        int t = (tid >= off) ? sm[tid - off] : 0;
        __syncthreads();
        sm[tid] += t;
        __syncthreads();
    }
    if (tid < B_BIN) blk_base[tid * NBUCK + k] = sm[tid] - v;   // exclusive
    if (tid == 255) bucket_cnt[k] = sm[255];
}

// ---------------- scan 196 bucket counts (1 block) ----------------
__global__ __launch_bounds__(256) void k_scan_buckets(const int* __restrict__ bucket_cnt,
                                                      int* __restrict__ bucket_base) {
    __shared__ int sm[256];
    const int tid = threadIdx.x;
    int v = (tid < NBUCK) ? bucket_cnt[tid] : 0;
    sm[tid] = v;
    __syncthreads();
    #pragma unroll
    for (int off = 1; off < 256; off <<= 1) {
        int t = (tid >= off) ? sm[tid - off] : 0;
        __syncthreads();
        sm[tid] += t;
        __syncthreads();
    }
    if (tid < NBUCK) bucket_base[tid] = sm[tid] - v;   // exclusive
    if (tid == 0) bucket_base[NBUCK] = N_EDGES;
}

// ---------------- pass A2: place packed edges into bucket-contiguous ebuf ----------------
__global__ __launch_bounds__(256) void k_bin_place(const int* __restrict__ ei,
                                                   const int* __restrict__ bucket_base,
                                                   const int* __restrict__ blk_base,
                                                   unsigned int* __restrict__ ebuf) {
    __shared__ int h[NBUCK];
    const int tid = threadIdx.x, b = blockIdx.x;
    for (int i = tid; i < NBUCK; i += 256) h[i] = 0;
    __syncthreads();
    const int e0 = b * CHUNK;
    for (int i = tid; i < CHUNK; i += 256) {
        int s = ei[e0 + i];
        int d = ei[N_EDGES + e0 + i];
        int k = d >> 8;
        int loc = atomicAdd(&h[k], 1);
        int pos = bucket_base[k] + blk_base[b * NBUCK + k] + loc;
        ebuf[pos] = ((unsigned int)s << 8) | (unsigned int)(d & 255);
    }
}

// ---------------- pass B: per-bucket exact CSR (rowptr, col, dinv) ----------------
__global__ __launch_bounds__(256) void k_bucket_csr(const unsigned int* __restrict__ ebuf,
                                                    const int* __restrict__ bucket_base,
                                                    int* __restrict__ rowptr,
                                                    int* __restrict__ col,
                                                    float* __restrict__ dinv) {
    __shared__ int cnts[256];
    __shared__ int fillc[256];
    __shared__ int sm[256];
    const int tid = threadIdx.x, k = blockIdx.x;
    const int node0 = k << 8;
    const int e0 = bucket_base[k], e1 = bucket_base[k + 1];
    const int cnt = e1 - e0;

    cnts[tid] = 0;
    __syncthreads();
    for (int i = tid; i < cnt; i += 256)
        atomicAdd(&cnts[ebuf[e0 + i] & 255], 1);
    __syncthreads();

    int v = cnts[tid];
    sm[tid] = v;
    __syncthreads();
    #pragma unroll
    for (int off = 1; off < 256; off <<= 1) {
        int t = (tid >= off) ? sm[tid - off] : 0;
        __syncthreads();
        sm[tid] += t;
        __syncthreads();
    }
    int rp = sm[tid] - v;              // exclusive prefix within bucket
    fillc[tid] = rp;
    int node = node0 + tid;
    if (node < N_NODES) {
        rowptr[node] = e0 + rp;
        dinv[node] = rsqrtf((float)(v + 1));   // +1 self loop
    }
    if (k == NBUCK - 1 && tid == 0) rowptr[N_NODES] = N_EDGES;
    __syncthreads();

    for (int i = tid; i < cnt; i += 256) {
        unsigned int pv = ebuf[e0 + i];
        int j = pv & 255;
        int loc = atomicAdd(&fillc[j], 1);
        col[e0 + loc] = (int)(pv >> 8);        // writes stay in this bucket's 16 KB window
    }
}

// ---------------- W transpose to bf16: Wt[n][k] = bf16(W[k][n]) ----------------
// grid 2: blockIdx selects (W1->Wt1, W2->Wt2)
__global__ __launch_bounds__(256) void k_wt(const float* __restrict__ Wa,
                                            const float* __restrict__ Wb,
                                            unsigned short* __restrict__ Wta,
                                            unsigned short* __restrict__ Wtb) {
    const float* W = blockIdx.x ? Wb : Wa;
    unsigned short* Wt = blockIdx.x ? Wtb : Wta;
    const int tid = threadIdx.x;
    for (int i = 0; i < 64; ++i) {
        int idx = i * 256 + tid;           // n*128 + k
        int n = idx >> 7, kk = idx & 127;
        Wt[idx] = f2bf(W[kk * CH + n]);
    }
}

// ---------------- X -> bf16 (8 elems/thread) ----------------
__global__ __launch_bounds__(256) void k_xb(const float* __restrict__ X,
                                            unsigned short* __restrict__ XB) {
    int t = blockIdx.x * 256 + threadIdx.x;     // 800000 threads exactly
    int base = t * 8;
    float4 a = *(const float4*)&X[base];
    float4 b = *(const float4*)&X[base + 4];
    ushort4 lo, hi;
    lo.x = f2bf(a.x); lo.y = f2bf(a.y); lo.z = f2bf(a.z); lo.w = f2bf(a.w);
    hi.x = f2bf(b.x); hi.y = f2bf(b.y); hi.z = f2bf(b.z); hi.w = f2bf(b.w);
    *(ushort4*)&XB[base] = lo;
    *(ushort4*)&XB[base + 4] = hi;
}

// ---------------- MFMA GEMM: HS(bf16) = (A @ W) * dinv[row] ----------------
// 4 waves/block, 16 rows/wave (64 rows/block). A row-major bf16; Wt = W^T row-major bf16.
// frag: lane l -> 16-dim index (l&15), k-chunk (l>>4)*8, contiguous bf16x8 (k-permutation
// consistent across A and B, so any HW k-order gives the correct dot product).
// C/D (HW-verified): col = l&15, row = (l>>4)*4 + reg.
__global__ __launch_bounds__(256) void k_gemm_mfma(
        const unsigned short* __restrict__ A,    // [N][128] bf16
        const unsigned short* __restrict__ Wt,   // [128][128] bf16, n-major
        const float* __restrict__ dinv,
        unsigned short* __restrict__ HS) {
    const int tid = threadIdx.x;
    const int l = tid & 63, w = tid >> 6;
    const int lm = l & 15, lk = l >> 4;
    const int row0 = blockIdx.x * 64 + w * 16;

    int arow = row0 + lm;
    if (arow >= N_NODES) arow = N_NODES - 1;     // clamp (masked on store)
    bf16x8 a[4];
    #pragma unroll
    for (int ki = 0; ki < 4; ++ki)
        a[ki] = *(const bf16x8*)&A[arow * CH + ki * 32 + lk * 8];

    float dv[4];
    int rowr[4];
    #pragma unroll
    for (int r = 0; r < 4; ++r) {
        rowr[r] = row0 + lk * 4 + r;
        dv[r] = dinv[rowr[r] < N_NODES ? rowr[r] : 0];
    }

    #pragma unroll
    for (int ct = 0; ct < 8; ++ct) {
        const unsigned short* wp = &Wt[(ct * 16 + lm) * CH + lk * 8];
        f32x4 acc = {0.f, 0.f, 0.f, 0.f};
        #pragma unroll
        for (int ki = 0; ki < 4; ++ki) {
            bf16x8 bfrag = *(const bf16x8*)&wp[ki * 32];
            acc = __builtin_amdgcn_mfma_f32_16x16x32_bf16(a[ki], bfrag, acc, 0, 0, 0);
        }
        #pragma unroll
        for (int r = 0; r < 4; ++r) {
            if (rowr[r] < N_NODES)
                HS[rowr[r] * CH + ct * 16 + lm] = f2bf(acc[r] * dv[r]);
        }
    }
}

// ---------------- aggregate: relu(dinv*(HS[self] + sum HS[col]) + b) ----------------
// MODE 0: write bf16 (next layer input). MODE 1: write f32 (final output).
template <int MODE>
__global__ __launch_bounds__(256) void k_aggregate(
        const int* __restrict__ rowptr, const int* __restrict__ col,
        const unsigned short* __restrict__ HS, const float* __restrict__ dinv,
        const float* __restrict__ b, float* __restrict__ OUTF,
        unsigned short* __restrict__ OUTB) {
    int gid = blockIdx.x * 256 + threadIdx.x;
    int node = gid >> 5;
    if (node >= N_NODES) return;
    int lane = gid & 31;
    const ushort4* H4 = (const ushort4*)HS;    // 32 ushort4 per row

    int e0 = rowptr[node];
    int e1 = rowptr[node + 1];

    ushort4 hself = H4[node * 32 + lane];
    float ax = bf2f(hself.x), ay = bf2f(hself.y), az = bf2f(hself.z), aw = bf2f(hself.w);

    int e = e0;
    for (; e + 3 < e1; e += 4) {
        int s0 = col[e], s1 = col[e + 1], s2 = col[e + 2], s3 = col[e + 3];
        ushort4 v0 = H4[s0 * 32 + lane];
        ushort4 v1 = H4[s1 * 32 + lane];
        ushort4 v2 = H4[s2 * 32 + lane];
        ushort4 v3 = H4[s3 * 32 + lane];
        ax += (bf2f(v0.x) + bf2f(v1.x)) + (bf2f(v2.x) + bf2f(v3.x));
        ay += (bf2f(v0.y) + bf2f(v1.y)) + (bf2f(v2.y) + bf2f(v3.y));
        az += (bf2f(v0.z) + bf2f(v1.z)) + (bf2f(v2.z) + bf2f(v3.z));
        aw += (bf2f(v0.w) + bf2f(v1.w)) + (bf2f(v2.w) + bf2f(v3.w));
    }
    for (; e < e1; ++e) {
        ushort4 va = H4[col[e] * 32 + lane];
        ax += bf2f(va.x); ay += bf2f(va.y); az += bf2f(va.z); aw += bf2f(va.w);
    }

    float di = dinv[node];
    float4 bb = *(const float4*)&b[lane * 4];
    float ox = fmaxf(ax * di + bb.x, 0.f);
    float oy = fmaxf(ay * di + bb.y, 0.f);
    float oz = fmaxf(az * di + bb.z, 0.f);
    float ow = fmaxf(aw * di + bb.w, 0.f);
    if (MODE == 0) {
        ushort4 o;
        o.x = f2bf(ox); o.y = f2bf(oy); o.z = f2bf(oz); o.w = f2bf(ow);
        *(ushort4*)&OUTB[node * CH + lane * 4] = o;
    } else {
        *(float4*)&OUTF[node * CH + lane * 4] = make_float4(ox, oy, oz, ow);
    }
}

extern "C" void kernel_launch(void* const* d_in, const int* in_sizes, int n_in,
                              void* d_out, int out_size, void* d_ws, size_t ws_size,
                              hipStream_t stream) {
    const float* x  = (const float*)d_in[0];
    const int*   ei = (const int*)d_in[1];
    const float* W1 = (const float*)d_in[2];
    const float* b1 = (const float*)d_in[3];
    const float* W2 = (const float*)d_in[4];
    const float* b2 = (const float*)d_in[5];
    float* out = (float*)d_out;

    // workspace layout (4B units):
    int* blk_base    = (int*)d_ws;               // 250*196 = 49000 -> pad 49152
    int* bucket_cnt  = blk_base + 49152;         // 256
    int* bucket_base = bucket_cnt + 256;         // 256 (uses NBUCK+1)
    int* rowptr      = bucket_base + 256;        // 50001 -> pad 50176
    int* col         = rowptr + 50176;           // 800000 -> pad 800256
    float* dinv      = (float*)(col + 800256);   // 50000 -> pad 50176
    unsigned int* ebuf = (unsigned int*)(dinv + 50176);      // 800000 -> pad 800256
    unsigned short* xb  = (unsigned short*)(ebuf + 800256);  // 6.4M bf16
    unsigned short* hb  = xb + 6400000;                      // 6.4M bf16
    unsigned short* hs  = hb + 6400000;                      // 6.4M bf16
    unsigned short* wt1 = hs + 6400000;                      // 16384 bf16
    unsigned short* wt2 = wt1 + 16384;                       // 16384 bf16

    const int gG = (N_NODES + 63) / 64;              // 782
    const int gA = (N_NODES * 32 + 255) / 256;       // 6250
    const int gX = 3125;                             // 800000 threads exactly

    // ---- CSR build: two-level counting sort (no global atomics, no memset) ----
    k_bin_count<<<B_BIN, 256, 0, stream>>>(ei + N_EDGES, blk_base);
    k_colscan<<<NBUCK, 256, 0, stream>>>(blk_base, bucket_cnt);
    k_scan_buckets<<<1, 256, 0, stream>>>(bucket_cnt, bucket_base);
    k_bin_place<<<B_BIN, 256, 0, stream>>>(ei, bucket_base, blk_base, ebuf);
    k_bucket_csr<<<NBUCK, 256, 0, stream>>>(ebuf, bucket_base, rowptr, col, dinv);

    // ---- bf16 prep ----
    k_wt<<<2, 256, 0, stream>>>(W1, W2, wt1, wt2);
    k_xb<<<gX, 256, 0, stream>>>(x, xb);

    // ---- layer 1 ----
    k_gemm_mfma<<<gG, 256, 0, stream>>>(xb, wt1, dinv, hs);
    k_aggregate<0><<<gA, 256, 0, stream>>>(rowptr, col, hs, dinv, b1, nullptr, hb);

    // ---- layer 2 ----
    k_gemm_mfma<<<gG, 256, 0, stream>>>(hb, wt2, dinv, hs);
    k_aggregate<1><<<gA, 256, 0, stream>>>(rowptr, col, hs, dinv, b2, out, nullptr);
}